// Round 1
// baseline (86.742 us; speedup 1.0000x reference)
//
#include <hip/hip_runtime.h>

// CenterLoss: out = mean_i( clip( ||x_i - centers[label_i]||^2, 1e-12, 1e12 ) )
// x: (4096, 512) f32, labels: (4096,) int, centers: (10000, 512) f32, out: scalar f32.
//
// Key algorithmic fusion: the reference builds a (4096 x 10000) distmat and
// gathers one column per row. We compute only the gathered entries directly:
// ~16 MB of traffic instead of a 40-GFLOP GEMM. Memory-bound, roofline ~2.6us.

#define NROWS 4096
#define DIM 512
#define WAVES_PER_BLOCK 4   // 256 threads/block, one wave per row

__global__ __launch_bounds__(64 * WAVES_PER_BLOCK)
void center_loss_kernel(const float* __restrict__ x,
                        const int* __restrict__ labels,
                        const float* __restrict__ centers,
                        float* __restrict__ out) {
    const int wave_in_block = threadIdx.x >> 6;     // 0..3
    const int lane          = threadIdx.x & 63;     // 0..63
    const int row = blockIdx.x * WAVES_PER_BLOCK + wave_in_block;

    __shared__ float s_partial[WAVES_PER_BLOCK];

    float sum = 0.0f;
    if (row < NROWS) {
        const int label = labels[row];
        const float4* __restrict__ xr = (const float4*)(x + (size_t)row * DIM);
        const float4* __restrict__ cr = (const float4*)(centers + (size_t)label * DIM);
        // 512 floats = 128 float4 per row; 64 lanes -> 2 float4 each (16B/lane).
        #pragma unroll
        for (int i = 0; i < 2; ++i) {
            const float4 a = xr[lane + i * 64];
            const float4 b = cr[lane + i * 64];
            const float dx = a.x - b.x;
            const float dy = a.y - b.y;
            const float dz = a.z - b.z;
            const float dw = a.w - b.w;
            sum += dx * dx + dy * dy + dz * dz + dw * dw;
        }
    }

    // wave-64 shuffle reduction
    #pragma unroll
    for (int off = 32; off > 0; off >>= 1)
        sum += __shfl_down(sum, off, 64);

    if (lane == 0) {
        float d = (row < NROWS) ? fminf(fmaxf(sum, 1e-12f), 1e12f) : 0.0f;
        s_partial[wave_in_block] = d;
    }
    __syncthreads();

    if (threadIdx.x == 0) {
        float block_sum = 0.0f;
        #pragma unroll
        for (int w = 0; w < WAVES_PER_BLOCK; ++w)
            block_sum += s_partial[w];
        // fold the mean into the accumulation; one atomic per block (1024 total)
        atomicAdd(out, block_sum * (1.0f / (float)NROWS));
    }
}

extern "C" void kernel_launch(void* const* d_in, const int* in_sizes, int n_in,
                              void* d_out, int out_size, void* d_ws, size_t ws_size,
                              hipStream_t stream) {
    const float* x       = (const float*)d_in[0];
    const int*   labels  = (const int*)d_in[1];
    const float* centers = (const float*)d_in[2];
    float* out = (float*)d_out;

    // d_out is poisoned to 0xAA before every call; zero it on-stream
    // (hipMemsetAsync is graph-capture safe).
    hipMemsetAsync(out, 0, sizeof(float), stream);

    const int blocks = NROWS / WAVES_PER_BLOCK;  // 1024
    center_loss_kernel<<<blocks, 64 * WAVES_PER_BLOCK, 0, stream>>>(
        x, labels, centers, out);
}

// Round 2
// 73.401 us; speedup vs baseline: 1.1818x; 1.1818x over previous
//
#include <hip/hip_runtime.h>

// CenterLoss: out = mean_i( clip( ||x_i - centers[label_i]||^2, 1e-12, 1e12 ) )
// x: (4096, 512) f32, labels: (4096,) int64->int32 view, centers: (10000, 512) f32.
//
// Fused gather form: only the 4096 labeled distances are computed (~15 MB
// traffic), never the (4096 x 10000) distmat.
//
// R2 change vs R1: removed the hipMemsetAsync node and the 1024 same-address
// atomicAdds (cross-XCD serialized RMW suspect). Block partials go to d_ws
// with plain stores; a second 1-block kernel reduces them and writes out once.

#define NROWS 4096
#define DIM 512
#define WAVES_PER_BLOCK 4   // 256 threads/block, one wave per row
#define NBLOCKS (NROWS / WAVES_PER_BLOCK)   // 1024 partials

__global__ __launch_bounds__(64 * WAVES_PER_BLOCK)
void center_loss_kernel(const float* __restrict__ x,
                        const int* __restrict__ labels,
                        const float* __restrict__ centers,
                        float* __restrict__ partials) {
    const int wave_in_block = threadIdx.x >> 6;     // 0..3
    const int lane          = threadIdx.x & 63;     // 0..63
    const int row = blockIdx.x * WAVES_PER_BLOCK + wave_in_block;

    __shared__ float s_partial[WAVES_PER_BLOCK];

    const int label = labels[row];
    const float4* __restrict__ xr = (const float4*)(x + (size_t)row * DIM);
    const float4* __restrict__ cr = (const float4*)(centers + (size_t)label * DIM);

    // 512 floats = 128 float4 per row; 64 lanes -> 2 float4 each (16B/lane).
    float sum = 0.0f;
    #pragma unroll
    for (int i = 0; i < 2; ++i) {
        const float4 a = xr[lane + i * 64];
        const float4 b = cr[lane + i * 64];
        const float dx = a.x - b.x;
        const float dy = a.y - b.y;
        const float dz = a.z - b.z;
        const float dw = a.w - b.w;
        sum += dx * dx + dy * dy + dz * dz + dw * dw;
    }

    // wave-64 shuffle reduction
    #pragma unroll
    for (int off = 32; off > 0; off >>= 1)
        sum += __shfl_down(sum, off, 64);

    if (lane == 0)
        s_partial[wave_in_block] = fminf(fmaxf(sum, 1e-12f), 1e12f);
    __syncthreads();

    if (threadIdx.x == 0) {
        partials[blockIdx.x] = s_partial[0] + s_partial[1] +
                               s_partial[2] + s_partial[3];
    }
}

__global__ __launch_bounds__(1024)
void reduce_kernel(const float* __restrict__ partials,
                   float* __restrict__ out) {
    const int lane = threadIdx.x & 63;
    const int wave = threadIdx.x >> 6;   // 0..15

    __shared__ float s[16];

    float v = partials[threadIdx.x];
    #pragma unroll
    for (int off = 32; off > 0; off >>= 1)
        v += __shfl_down(v, off, 64);
    if (lane == 0) s[wave] = v;
    __syncthreads();

    if (wave == 0) {
        float t = (lane < 16) ? s[lane] : 0.0f;
        #pragma unroll
        for (int off = 8; off > 0; off >>= 1)
            t += __shfl_down(t, off, 64);
        if (lane == 0) out[0] = t * (1.0f / (float)NROWS);
    }
}

extern "C" void kernel_launch(void* const* d_in, const int* in_sizes, int n_in,
                              void* d_out, int out_size, void* d_ws, size_t ws_size,
                              hipStream_t stream) {
    const float* x       = (const float*)d_in[0];
    const int*   labels  = (const int*)d_in[1];
    const float* centers = (const float*)d_in[2];
    float* out      = (float*)d_out;
    float* partials = (float*)d_ws;   // 1024 floats, overwritten every call

    center_loss_kernel<<<NBLOCKS, 64 * WAVES_PER_BLOCK, 0, stream>>>(
        x, labels, centers, partials);
    reduce_kernel<<<1, 1024, 0, stream>>>(partials, out);
}